// Round 1
// baseline (210.685 us; speedup 1.0000x reference)
//
#include <hip/hip_runtime.h>
#include <hip/hip_bf16.h>
#include <cstdint>

#define B_ 16
#define T_ 2048
#define C_ 768
#define H_ 128

typedef __bf16 bf16x8 __attribute__((ext_vector_type(8)));
typedef float f32x4 __attribute__((ext_vector_type(4)));
typedef unsigned short u16x8 __attribute__((ext_vector_type(8)));

// async global->LDS, 16B per lane; LDS dest is wave-uniform base (+lane*16 implicit)
__device__ __forceinline__ void gld_lds16(const void* g, void* s) {
    __builtin_amdgcn_global_load_lds(
        (__attribute__((address_space(1))) void*)(size_t)g,
        (__attribute__((address_space(3))) void*)s,
        16, 0, 0);
}

__device__ __forceinline__ unsigned short f2bf(float f) {
    __bf16 h = (__bf16)f;
    return __builtin_bit_cast(unsigned short, h);
}

// ---- kernel 1: weight transpose+cvt only (x conversion fused into proj)
__global__ __launch_bounds__(256) void wconv_kernel(
    const float* __restrict__ Wq, const float* __restrict__ Wk,
    const float* __restrict__ Wv, unsigned short* __restrict__ wT) {
    int idx = blockIdx.x * 256 + threadIdx.x;
    if (idx >= 3 * H_ * C_) return;
    int w = idx / (H_ * C_);
    int r = idx % (H_ * C_);
    int h = r / C_;
    int c = r % C_;
    const float* W = (w == 0) ? Wq : ((w == 1) ? Wk : Wv);
    wT[idx] = f2bf(W[c * H_ + h]);
}

// ---- kernel 2: merged QKV proj, double-buffered, fused fp32->bf16 A-staging.
__global__ __launch_bounds__(512, 2) void proj_kernel(
    const float* __restrict__ x, const unsigned short* __restrict__ wT,
    unsigned short* __restrict__ qb, unsigned short* __restrict__ kb,
    unsigned short* __restrict__ vtb) {
    __shared__ unsigned short Asm[2][128 * 64];  // 2x16 KB, swizzle ^(m&7)
    __shared__ unsigned short Bsm[2][192 * 64];  // 2x24 KB, swizzle ^(n&7)

    const int tid = threadIdx.x;
    const int nh = blockIdx.x & 1;
    const int m0 = (blockIdx.x >> 1) * 128;
    const int wid = tid >> 6;
    const int lane = tid & 63;
    const int quad = lane >> 4;
    const int lo16 = lane & 15;
    const int mh = (wid >> 2) * 64;       // wave's m-half
    const int wnl = (wid & 3) * 48;       // wave's n-slice within the 192
    const unsigned short* wTn = wT + (size_t)nh * 192 * C_;  // flat [384][768]

    f32x4 acc[4][3] = {};
    f32x4 pre[4];

    // ---- prologue: stage kt=0
#pragma unroll
    for (int r = 0; r < 2; ++r) {
        int cidx = r * 512 + tid;
        int m = cidx >> 3, lc = cidx & 7;
        const float* src = x + (size_t)(m0 + m) * C_ + lc * 8;
        pre[r * 2] = *(const f32x4*)src;
        pre[r * 2 + 1] = *(const f32x4*)(src + 4);
    }
#pragma unroll
    for (int r = 0; r < 3; ++r) {
        int cidx = r * 512 + tid;
        int n = cidx >> 3, c = (cidx & 7) ^ (n & 7);
        gld_lds16((const char*)wTn + ((size_t)n * C_ + c * 8) * 2,
                  (char*)&Bsm[0][0] + (r * 512 + wid * 64) * 16);
    }
#pragma unroll
    for (int r = 0; r < 2; ++r) {
        int cidx = r * 512 + tid;
        int m = cidx >> 3, lc = cidx & 7;
        u16x8 o;
        o[0] = f2bf(pre[r * 2][0]); o[1] = f2bf(pre[r * 2][1]);
        o[2] = f2bf(pre[r * 2][2]); o[3] = f2bf(pre[r * 2][3]);
        o[4] = f2bf(pre[r * 2 + 1][0]); o[5] = f2bf(pre[r * 2 + 1][1]);
        o[6] = f2bf(pre[r * 2 + 1][2]); o[7] = f2bf(pre[r * 2 + 1][3]);
        *(u16x8*)(&Asm[0][m * 64 + (lc ^ (m & 7)) * 8]) = o;
    }

    for (int kt = 0; kt < 12; ++kt) {
        const int p = kt & 1;
        __syncthreads();  // drains stage(kt): vmcnt (B) + lgkm (A writes)
        if (kt + 1 < 12) {
            const int k1 = (kt + 1) * 64;
#pragma unroll
            for (int r = 0; r < 2; ++r) {
                int cidx = r * 512 + tid;
                int m = cidx >> 3, lc = cidx & 7;
                const float* src = x + (size_t)(m0 + m) * C_ + k1 + lc * 8;
                pre[r * 2] = *(const f32x4*)src;
                pre[r * 2 + 1] = *(const f32x4*)(src + 4);
            }
#pragma unroll
            for (int r = 0; r < 3; ++r) {
                int cidx = r * 512 + tid;
                int n = cidx >> 3, c = (cidx & 7) ^ (n & 7);
                gld_lds16((const char*)wTn + ((size_t)n * C_ + k1 + c * 8) * 2,
                          (char*)&Bsm[p ^ 1][0] + (r * 512 + wid * 64) * 16);
            }
        }

        // compute on buffer p
#pragma unroll
        for (int kk = 0; kk < 2; ++kk) {
            bf16x8 af[4], bf[3];
#pragma unroll
            for (int mi = 0; mi < 4; ++mi) {
                int m = mh + mi * 16 + lo16;
                int c = (kk * 4 + quad) ^ (m & 7);
                af[mi] = *(const bf16x8*)((const __bf16*)&Asm[p][0] + m * 64 + c * 8);
            }
#pragma unroll
            for (int ni = 0; ni < 3; ++ni) {
                int n = wnl + ni * 16 + lo16;
                int c = (kk * 4 + quad) ^ (n & 7);
                bf[ni] = *(const bf16x8*)((const __bf16*)&Bsm[p][0] + n * 64 + c * 8);
            }
#pragma unroll
            for (int mi = 0; mi < 4; ++mi)
#pragma unroll
                for (int ni = 0; ni < 3; ++ni)
                    acc[mi][ni] = __builtin_amdgcn_mfma_f32_16x16x32_bf16(
                        af[mi], bf[ni], acc[mi][ni], 0, 0, 0);
        }

        if (kt + 1 < 12) {
#pragma unroll
            for (int r = 0; r < 2; ++r) {
                int cidx = r * 512 + tid;
                int m = cidx >> 3, lc = cidx & 7;
                u16x8 o;
                o[0] = f2bf(pre[r * 2][0]); o[1] = f2bf(pre[r * 2][1]);
                o[2] = f2bf(pre[r * 2][2]); o[3] = f2bf(pre[r * 2][3]);
                o[4] = f2bf(pre[r * 2 + 1][0]); o[5] = f2bf(pre[r * 2 + 1][1]);
                o[6] = f2bf(pre[r * 2 + 1][2]); o[7] = f2bf(pre[r * 2 + 1][3]);
                *(u16x8*)(&Asm[p ^ 1][m * 64 + (lc ^ (m & 7)) * 8]) = o;
            }
        }
    }

    // epilogue; C/D: col = lane&15, row = quad*4 + reg
#pragma unroll
    for (int mi = 0; mi < 4; ++mi) {
        int grow = m0 + mh + mi * 16 + quad * 4;
#pragma unroll
        for (int ni = 0; ni < 3; ++ni) {
            int n = nh * 192 + wnl + ni * 16 + lo16;
            int wmat = n >> 7;
            int col = n & 127;
            if (wmat < 2) {
                unsigned short* o = (wmat == 0) ? qb : kb;
#pragma unroll
                for (int rr = 0; rr < 4; ++rr)
                    o[(size_t)(grow + rr) * H_ + col] = f2bf(acc[mi][ni][rr]);
            } else {
                int b = grow >> 11;
                int t = grow & 2047;
                ushort4 pk;
                pk.x = f2bf(acc[mi][ni][0]); pk.y = f2bf(acc[mi][ni][1]);
                pk.z = f2bf(acc[mi][ni][2]); pk.w = f2bf(acc[mi][ni][3]);
                *(ushort4*)(vtb + ((size_t)b * H_ + col) * T_ + t) = pk;
            }
        }
    }
}

// ---- attn staging (512 threads): K tile + V tile into buffer p
__device__ __forceinline__ void attn_stage(
    const unsigned short* kB, const unsigned short* vB, int kv0, int p,
    unsigned short* Ks, unsigned short* Vs, int tid, int wid) {
#pragma unroll
    for (int rnd = 0; rnd < 2; ++rnd) {
        int cidx = rnd * 512 + tid;
        int m = cidx >> 4;
        int c = (cidx & 15) ^ (m & 15);
        gld_lds16((const char*)kB + ((size_t)(kv0 + m) * H_ + c * 8) * 2,
                  (char*)(Ks + p * 64 * 128) + (rnd * 512 + wid * 64) * 16);
    }
#pragma unroll
    for (int rnd = 0; rnd < 2; ++rnd) {
        int cidx = rnd * 512 + tid;
        int d = cidx >> 3;
        int c = (cidx & 7) ^ (d & 7);
        gld_lds16((const char*)vB + ((size_t)d * T_ + kv0 + c * 8) * 2,
                  (char*)(Vs + p * 128 * 64) + (rnd * 512 + wid * 64) * 16);
    }
}

// ---- attn segment: kv tiles [j0,j1), double-buffered K/V staging.
// 8 waves: wave = (kvh, qg). Wave handles kv rows [kvh*32, kvh*32+32) of each
// tile for q rows [qg*16, qg*16+16) of the 64-row q tile. Partials additive.
__device__ __forceinline__ void attn_seg(
    const unsigned short* kB, const unsigned short* vB, const bf16x8 qfrag[4],
    int j0, int j1, int jmask, float& l_part, f32x4 oacc[8],
    unsigned short* Ks, unsigned short* Vs, unsigned short* Pw,
    int tid, int wid, int quad, int lo16, int qg, int kvh) {
    const float cs = 0.05205877694341f;  // 768^-0.5 * log2(e)
    __syncthreads();  // prior segment's buffer readers done
    attn_stage(kB, vB, j0 * 64, 0, Ks, Vs, tid, wid);
    for (int j = j0; j < j1; ++j) {
        const int p = (j - j0) & 1;
        __syncthreads();  // drains stage(j)
        if (j + 1 < j1) attn_stage(kB, vB, (j + 1) * 64, p ^ 1, Ks, Vs, tid, wid);

        const unsigned short* Kp = Ks + p * 64 * 128;
        const unsigned short* Vp = Vs + p * 128 * 64;

        // S^T = K Q^T: 32 kv rows (this group's half) x 16 q cols per wave
        f32x4 s[2] = {};
#pragma unroll
        for (int ks = 0; ks < 4; ++ks) {
#pragma unroll
            for (int ni = 0; ni < 2; ++ni) {
                int row = kvh * 32 + ni * 16 + lo16;
                int slot = (ks * 4 + quad) ^ lo16;
                bf16x8 kf = *(const bf16x8*)((const __bf16*)Kp + row * 128 + slot * 8);
                s[ni] = __builtin_amdgcn_mfma_f32_16x16x32_bf16(kf, qfrag[ks], s[ni], 0, 0, 0);
            }
        }

        const bool diag = (j == jmask);
        if (diag) {
#pragma unroll
            for (int ni = 0; ni < 2; ++ni) {
#pragma unroll
                for (int rr = 0; rr < 4; ++rr) {
                    float pv = exp2f(s[ni][rr] * cs);
                    if (kvh * 32 + ni * 16 + quad * 4 + rr > qg * 16 + lo16) pv = 0.f;
                    l_part += pv;
                    s[ni][rr] = pv;
                }
                ushort4 w4;
                w4.x = f2bf(s[ni][0]); w4.y = f2bf(s[ni][1]);
                w4.z = f2bf(s[ni][2]); w4.w = f2bf(s[ni][3]);
                *(ushort4*)(Pw + lo16 * 40 + ni * 16 + quad * 4) = w4;
            }
        } else {
#pragma unroll
            for (int ni = 0; ni < 2; ++ni) {
#pragma unroll
                for (int rr = 0; rr < 4; ++rr) {
                    float pv = exp2f(s[ni][rr] * cs);
                    l_part += pv;
                    s[ni][rr] = pv;
                }
                ushort4 w4;
                w4.x = f2bf(s[ni][0]); w4.y = f2bf(s[ni][1]);
                w4.z = f2bf(s[ni][2]); w4.w = f2bf(s[ni][3]);
                *(ushort4*)(Pw + lo16 * 40 + ni * 16 + quad * 4) = w4;
            }
        }

        // O += P V (this group's 32 kv rows only; single k-slice of 32)
        bf16x8 pf = *(const bf16x8*)((const __bf16*)Pw + lo16 * 40 + quad * 8);
#pragma unroll
        for (int nd = 0; nd < 8; ++nd) {
            int dn = nd * 16 + lo16;
            int vc = (kvh * 4 + quad) ^ (dn & 7);
            bf16x8 vf = *(const bf16x8*)((const __bf16*)Vp + dn * 64 + vc * 8);
            oacc[nd] = __builtin_amdgcn_mfma_f32_16x16x32_bf16(pf, vf, oacc[nd], 0, 0, 0);
        }
    }
}

__device__ __forceinline__ void load_qfrag(const unsigned short* qB, int q0,
                                           int qg, int quad, int lo16, bf16x8 qf[4]) {
    const unsigned short* qrow = qB + (size_t)(q0 + qg * 16 + lo16) * H_ + quad * 8;
#pragma unroll
    for (int ks = 0; ks < 4; ++ks) qf[ks] = *(const bf16x8*)(qrow + ks * 32);
}

// cross-group reduce: in-wave l reduce, then kvh=1 waves publish O,l via LDS
// (XOR-swizzled, conflict-free) and kvh=0 waves accumulate. Once per segment.
__device__ __forceinline__ void xgroup_reduce(
    float& l_part, f32x4 oacc[8], unsigned short* KsBase, float* Lred,
    int lane, int qg, int kvh) {
    l_part += __shfl_xor(l_part, 16);
    l_part += __shfl_xor(l_part, 32);
    __syncthreads();  // all waves done reading K/V LDS
    float* red = (float*)KsBase;
    if (kvh == 1) {
        float* dst = red + (size_t)(qg * 64 + lane) * 32;
#pragma unroll
        for (int nd = 0; nd < 8; ++nd)
            *(f32x4*)(dst + ((nd ^ (lane & 7)) * 4)) = oacc[nd];
        Lred[qg * 64 + lane] = l_part;
    }
    __syncthreads();
    if (kvh == 0) {
        const float* src = red + (size_t)(qg * 64 + lane) * 32;
#pragma unroll
        for (int nd = 0; nd < 8; ++nd) {
            f32x4 t = *(const f32x4*)(src + ((nd ^ (lane & 7)) * 4));
            oacc[nd][0] += t[0]; oacc[nd][1] += t[1];
            oacc[nd][2] += t[2]; oacc[nd][3] += t[3];
        }
        l_part += Lred[qg * 64 + lane];
    }
}

// ---- kernel 3: balanced causal flash attention, 8 waves with kv-split.
__global__ __launch_bounds__(512, 4) void attn_kernel(
    const unsigned short* __restrict__ qb, const unsigned short* __restrict__ kb,
    const unsigned short* __restrict__ vtb, float* __restrict__ out,
    float* __restrict__ pO, float* __restrict__ pL) {
    __shared__ unsigned short Ks[2][64 * 128];   // 32 KB (also reduce scratch)
    __shared__ unsigned short Vs[2][128 * 64];   // 32 KB
    __shared__ unsigned short Ps[8][16 * 40];    // 10 KB
    __shared__ float Lred[256];                  // 1 KB

    const int tid = threadIdx.x;
    const int bid = blockIdx.x;
    const int half = bid >> 8;
    const int slot = bid & 255;
    const int r = slot >> 4;
    const int b = slot & 15;

    const unsigned short* qB = qb + (size_t)b * T_ * H_;
    const unsigned short* kB = kb + (size_t)b * T_ * H_;
    const unsigned short* vB = vtb + (size_t)b * H_ * T_;

    const int wid = tid >> 6;
    const int lane = tid & 63;
    const int quad = lane >> 4;
    const int lo16 = lane & 15;
    const int qg = wid & 3;     // q-row group within 64-row tile
    const int kvh = wid >> 2;   // kv-half of each 64-row kv tile
    unsigned short* Pw = &Ps[wid][0];

    const int qtb = 31 - r;
    bf16x8 qf[4];
    float l_part = 0.f;
    f32x4 oacc[8] = {};

    if (half == 0) {
        // tile A (qt = r): full, direct output
        load_qfrag(qB, r * 64, qg, quad, lo16, qf);
        attn_seg(kB, vB, qf, 0, r + 1, r, l_part, oacc, &Ks[0][0], &Vs[0][0], Pw,
                 tid, wid, quad, lo16, qg, kvh);
        xgroup_reduce(l_part, oacc, &Ks[0][0], Lred, lane, qg, kvh);
        if (kvh == 0) {
#pragma unroll
            for (int rr = 0; rr < 4; ++rr) {
                float lv = __shfl(l_part, quad * 4 + rr);
                float inv = 1.0f / lv;
                int qrow = r * 64 + qg * 16 + quad * 4 + rr;
                float* orow = out + ((size_t)b * T_ + qrow) * H_;
#pragma unroll
                for (int nd = 0; nd < 8; ++nd)
                    orow[nd * 16 + lo16] = oacc[nd][rr] * inv;
            }
        }
        // tile B (qt = 31-r): kv units [0, 16-r), partial
        l_part = 0.f;
#pragma unroll
        for (int nd = 0; nd < 8; ++nd) oacc[nd] = f32x4{0.f, 0.f, 0.f, 0.f};
        load_qfrag(qB, qtb * 64, qg, quad, lo16, qf);
        attn_seg(kB, vB, qf, 0, 16 - r, -1, l_part, oacc, &Ks[0][0], &Vs[0][0], Pw,
                 tid, wid, quad, lo16, qg, kvh);
    } else {
        // tile B: kv units [16-r, 32-r), includes diagonal at j=31-r
        load_qfrag(qB, qtb * 64, qg, quad, lo16, qf);
        attn_seg(kB, vB, qf, 16 - r, 32 - r, qtb, l_part, oacc, &Ks[0][0], &Vs[0][0], Pw,
                 tid, wid, quad, lo16, qg, kvh);
    }

    // cross-group reduce + partial store for tile B (kvh==0 waves write)
    xgroup_reduce(l_part, oacc, &Ks[0][0], Lred, lane, qg, kvh);
    if (kvh == 0) {
        float* myO = pO + (size_t)(half * 256 + slot) * (64 * 128);
        if (lane < 16) pL[(half * 256 + slot) * 64 + qg * 16 + lo16] = l_part;
#pragma unroll
        for (int rr = 0; rr < 4; ++rr) {
            int ql = qg * 16 + quad * 4 + rr;
#pragma unroll
            for (int nd = 0; nd < 8; ++nd)
                myO[ql * 128 + nd * 16 + lo16] = oacc[nd][rr];
        }
    }
}

// ---- kernel 4: combine split partials for q-tiles 16..31
__global__ __launch_bounds__(256) void combine_kernel(
    const float* __restrict__ pO, const float* __restrict__ pL,
    float* __restrict__ out) {
    const int slot = blockIdx.x;
    const int r = slot >> 4;
    const int b = slot & 15;
    const int q0 = (31 - r) * 64;
    __shared__ float ls[64];
    const int tid = threadIdx.x;
    if (tid < 64) ls[tid] = pL[slot * 64 + tid] + pL[(256 + slot) * 64 + tid];
    __syncthreads();
    const float* O0 = pO + (size_t)slot * (64 * 128);
    const float* O1 = pO + (size_t)(256 + slot) * (64 * 128);
    float* ob = out + ((size_t)b * T_ + q0) * H_;
#pragma unroll
    for (int k = 0; k < 8; ++k) {
        int idx = (k * 256 + tid) * 4;
        f32x4 a = *(const f32x4*)(O0 + idx);
        f32x4 c = *(const f32x4*)(O1 + idx);
        float inv = 1.0f / ls[idx >> 7];
        f32x4 o;
        o[0] = (a[0] + c[0]) * inv; o[1] = (a[1] + c[1]) * inv;
        o[2] = (a[2] + c[2]) * inv; o[3] = (a[3] + c[3]) * inv;
        *(f32x4*)(ob + idx) = o;
    }
}

extern "C" void kernel_launch(void* const* d_in, const int* in_sizes, int n_in,
                              void* d_out, int out_size, void* d_ws, size_t ws_size,
                              hipStream_t stream) {
    const float* x = (const float*)d_in[0];
    const float* Wq = (const float*)d_in[1];
    const float* Wk = (const float*)d_in[2];
    const float* Wv = (const float*)d_in[3];
    float* out = (float*)d_out;

    char* ws = (char*)d_ws;
    unsigned short* wT  = (unsigned short*)ws;                    // 576 KB
    unsigned short* qb  = (unsigned short*)(ws + (1ull << 20));   // 8 MB
    unsigned short* kb  = (unsigned short*)(ws + (9ull << 20));   // 8 MB
    unsigned short* vtb = (unsigned short*)(ws + (17ull << 20));  // 8 MB
    float* pO = (float*)(ws + (80ull << 20));                     // 16.8 MB
    float* pL = (float*)(ws + (100ull << 20));                    // 128 KB

    hipLaunchKernelGGL(wconv_kernel, dim3(1152), dim3(256), 0, stream, Wq, Wk, Wv, wT);
    hipLaunchKernelGGL(proj_kernel, dim3(512), dim3(512), 0, stream, x, wT, qb, kb, vtb);
    hipLaunchKernelGGL(attn_kernel, dim3(512), dim3(512), 0, stream, qb, kb, vtb, out, pO, pL);
    hipLaunchKernelGGL(combine_kernel, dim3(256), dim3(256), 0, stream, pO, pL, out);
}

// Round 2
// 209.119 us; speedup vs baseline: 1.0075x; 1.0075x over previous
//
#include <hip/hip_runtime.h>
#include <hip/hip_bf16.h>
#include <cstdint>

#define B_ 16
#define T_ 2048
#define C_ 768
#define H_ 128

typedef __bf16 bf16x8 __attribute__((ext_vector_type(8)));
typedef float f32x4 __attribute__((ext_vector_type(4)));
typedef float f32x16 __attribute__((ext_vector_type(16)));
typedef unsigned short u16x8 __attribute__((ext_vector_type(8)));
typedef unsigned int u32x4 __attribute__((ext_vector_type(4)));

// async global->LDS, 16B per lane; LDS dest is wave-uniform base (+lane*16 implicit)
__device__ __forceinline__ void gld_lds16(const void* g, void* s) {
    __builtin_amdgcn_global_load_lds(
        (__attribute__((address_space(1))) void*)(size_t)g,
        (__attribute__((address_space(3))) void*)s,
        16, 0, 0);
}

__device__ __forceinline__ unsigned short f2bf(float f) {
    __bf16 h = (__bf16)f;
    return __builtin_bit_cast(unsigned short, h);
}

// ---- kernel 1: weight transpose+cvt only (x conversion fused into proj)
__global__ __launch_bounds__(256) void wconv_kernel(
    const float* __restrict__ Wq, const float* __restrict__ Wk,
    const float* __restrict__ Wv, unsigned short* __restrict__ wT) {
    int idx = blockIdx.x * 256 + threadIdx.x;
    if (idx >= 3 * H_ * C_) return;
    int w = idx / (H_ * C_);
    int r = idx % (H_ * C_);
    int h = r / C_;
    int c = r % C_;
    const float* W = (w == 0) ? Wq : ((w == 1) ? Wk : Wv);
    wT[idx] = f2bf(W[c * H_ + h]);
}

// ---- kernel 2: merged QKV proj, double-buffered, fused fp32->bf16 A-staging.
__global__ __launch_bounds__(512, 2) void proj_kernel(
    const float* __restrict__ x, const unsigned short* __restrict__ wT,
    unsigned short* __restrict__ qb, unsigned short* __restrict__ kb,
    unsigned short* __restrict__ vtb) {
    __shared__ unsigned short Asm[2][128 * 64];  // 2x16 KB, swizzle ^(m&7)
    __shared__ unsigned short Bsm[2][192 * 64];  // 2x24 KB, swizzle ^(n&7)

    const int tid = threadIdx.x;
    const int nh = blockIdx.x & 1;
    const int m0 = (blockIdx.x >> 1) * 128;
    const int wid = tid >> 6;
    const int lane = tid & 63;
    const int quad = lane >> 4;
    const int lo16 = lane & 15;
    const int mh = (wid >> 2) * 64;       // wave's m-half
    const int wnl = (wid & 3) * 48;       // wave's n-slice within the 192
    const unsigned short* wTn = wT + (size_t)nh * 192 * C_;  // flat [384][768]

    f32x4 acc[4][3] = {};
    f32x4 pre[4];

    // ---- prologue: stage kt=0
#pragma unroll
    for (int r = 0; r < 2; ++r) {
        int cidx = r * 512 + tid;
        int m = cidx >> 3, lc = cidx & 7;
        const float* src = x + (size_t)(m0 + m) * C_ + lc * 8;
        pre[r * 2] = *(const f32x4*)src;
        pre[r * 2 + 1] = *(const f32x4*)(src + 4);
    }
#pragma unroll
    for (int r = 0; r < 3; ++r) {
        int cidx = r * 512 + tid;
        int n = cidx >> 3, c = (cidx & 7) ^ (n & 7);
        gld_lds16((const char*)wTn + ((size_t)n * C_ + c * 8) * 2,
                  (char*)&Bsm[0][0] + (r * 512 + wid * 64) * 16);
    }
#pragma unroll
    for (int r = 0; r < 2; ++r) {
        int cidx = r * 512 + tid;
        int m = cidx >> 3, lc = cidx & 7;
        u16x8 o;
        o[0] = f2bf(pre[r * 2][0]); o[1] = f2bf(pre[r * 2][1]);
        o[2] = f2bf(pre[r * 2][2]); o[3] = f2bf(pre[r * 2][3]);
        o[4] = f2bf(pre[r * 2 + 1][0]); o[5] = f2bf(pre[r * 2 + 1][1]);
        o[6] = f2bf(pre[r * 2 + 1][2]); o[7] = f2bf(pre[r * 2 + 1][3]);
        *(u16x8*)(&Asm[0][m * 64 + (lc ^ (m & 7)) * 8]) = o;
    }

    for (int kt = 0; kt < 12; ++kt) {
        const int p = kt & 1;
        __syncthreads();  // drains stage(kt): vmcnt (B) + lgkm (A writes)
        if (kt + 1 < 12) {
            const int k1 = (kt + 1) * 64;
#pragma unroll
            for (int r = 0; r < 2; ++r) {
                int cidx = r * 512 + tid;
                int m = cidx >> 3, lc = cidx & 7;
                const float* src = x + (size_t)(m0 + m) * C_ + k1 + lc * 8;
                pre[r * 2] = *(const f32x4*)src;
                pre[r * 2 + 1] = *(const f32x4*)(src + 4);
            }
#pragma unroll
            for (int r = 0; r < 3; ++r) {
                int cidx = r * 512 + tid;
                int n = cidx >> 3, c = (cidx & 7) ^ (n & 7);
                gld_lds16((const char*)wTn + ((size_t)n * C_ + k1 + c * 8) * 2,
                          (char*)&Bsm[p ^ 1][0] + (r * 512 + wid * 64) * 16);
            }
        }

        // compute on buffer p
#pragma unroll
        for (int kk = 0; kk < 2; ++kk) {
            bf16x8 af[4], bf[3];
#pragma unroll
            for (int mi = 0; mi < 4; ++mi) {
                int m = mh + mi * 16 + lo16;
                int c = (kk * 4 + quad) ^ (m & 7);
                af[mi] = *(const bf16x8*)((const __bf16*)&Asm[p][0] + m * 64 + c * 8);
            }
#pragma unroll
            for (int ni = 0; ni < 3; ++ni) {
                int n = wnl + ni * 16 + lo16;
                int c = (kk * 4 + quad) ^ (n & 7);
                bf[ni] = *(const bf16x8*)((const __bf16*)&Bsm[p][0] + n * 64 + c * 8);
            }
#pragma unroll
            for (int mi = 0; mi < 4; ++mi)
#pragma unroll
                for (int ni = 0; ni < 3; ++ni)
                    acc[mi][ni] = __builtin_amdgcn_mfma_f32_16x16x32_bf16(
                        af[mi], bf[ni], acc[mi][ni], 0, 0, 0);
        }

        if (kt + 1 < 12) {
#pragma unroll
            for (int r = 0; r < 2; ++r) {
                int cidx = r * 512 + tid;
                int m = cidx >> 3, lc = cidx & 7;
                u16x8 o;
                o[0] = f2bf(pre[r * 2][0]); o[1] = f2bf(pre[r * 2][1]);
                o[2] = f2bf(pre[r * 2][2]); o[3] = f2bf(pre[r * 2][3]);
                o[4] = f2bf(pre[r * 2 + 1][0]); o[5] = f2bf(pre[r * 2 + 1][1]);
                o[6] = f2bf(pre[r * 2 + 1][2]); o[7] = f2bf(pre[r * 2 + 1][3]);
                *(u16x8*)(&Asm[p ^ 1][m * 64 + (lc ^ (m & 7)) * 8]) = o;
            }
        }
    }

    // epilogue; C/D: col = lane&15, row = quad*4 + reg
#pragma unroll
    for (int mi = 0; mi < 4; ++mi) {
        int grow = m0 + mh + mi * 16 + quad * 4;
#pragma unroll
        for (int ni = 0; ni < 3; ++ni) {
            int n = nh * 192 + wnl + ni * 16 + lo16;
            int wmat = n >> 7;
            int col = n & 127;
            if (wmat < 2) {
                unsigned short* o = (wmat == 0) ? qb : kb;
#pragma unroll
                for (int rr = 0; rr < 4; ++rr)
                    o[(size_t)(grow + rr) * H_ + col] = f2bf(acc[mi][ni][rr]);
            } else {
                int b = grow >> 11;
                int t = grow & 2047;
                ushort4 pk;
                pk.x = f2bf(acc[mi][ni][0]); pk.y = f2bf(acc[mi][ni][1]);
                pk.z = f2bf(acc[mi][ni][2]); pk.w = f2bf(acc[mi][ni][3]);
                *(ushort4*)(vtb + ((size_t)b * H_ + col) * T_ + t) = pk;
            }
        }
    }
}

// ---- attn staging (256 threads): K tile + V tile into buffer p
__device__ __forceinline__ void attn_stage(
    const unsigned short* kB, const unsigned short* vB, int kv0, int p,
    unsigned short* Ks, unsigned short* Vs, int tid, int wid) {
#pragma unroll
    for (int rnd = 0; rnd < 4; ++rnd) {
        int cidx = rnd * 256 + tid;
        int m = cidx >> 4;
        int c = (cidx & 15) ^ (m & 15);
        gld_lds16((const char*)kB + ((size_t)(kv0 + m) * H_ + c * 8) * 2,
                  (char*)(Ks + p * 64 * 128) + (rnd * 256 + wid * 64) * 16);
    }
#pragma unroll
    for (int rnd = 0; rnd < 4; ++rnd) {
        int cidx = rnd * 256 + tid;
        int d = cidx >> 3;
        int c = (cidx & 7) ^ (d & 7);
        gld_lds16((const char*)vB + ((size_t)d * T_ + kv0 + c * 8) * 2,
                  (char*)(Vs + p * 128 * 64) + (rnd * 256 + wid * 64) * 16);
    }
}

// ---- attn segment: kv tiles [j0,j1), double-buffered K/V staging.
// 4 waves of 32x32 MFMA: wave = (qh, kvh). QK^T -> S^T[kv32][q32] in regs,
// in-register softmax + cvt_pk/permlane pack, PV with V-frags. P never in LDS.
__device__ __forceinline__ void attn_seg(
    const unsigned short* kB, const unsigned short* vB, const bf16x8 qfrag[8],
    int j0, int j1, int jmask, int qbase, float& l_part, f32x16 oacc[4],
    unsigned short* Ks, unsigned short* Vs,
    int tid, int wid, int lane, int qh, int kvh) {
    const float cs = 0.05205877694341f;  // 768^-0.5 * log2(e)
    const int l31 = lane & 31;
    const int h8 = lane >> 5;
    const int rowbase = kvh * 32 + 4 * h8;  // + (r&3)+8*(r>>2) gives kv row in tile
    const int qglob = qbase + l31;          // this lane's q column (global)

    __syncthreads();  // prior segment's buffer/scratch readers done
    attn_stage(kB, vB, j0 * 64, 0, Ks, Vs, tid, wid);
    for (int j = j0; j < j1; ++j) {
        const int p = (j - j0) & 1;
        __syncthreads();  // drains stage(j)
        if (j + 1 < j1) attn_stage(kB, vB, (j + 1) * 64, p ^ 1, Ks, Vs, tid, wid);

        const unsigned short* Kp = Ks + p * 64 * 128;
        const unsigned short* Vp = Vs + p * 128 * 64;

        // S^T = K Q^T: one 32x32 block per wave; A row = kv = kvh*32+l31
        f32x16 s = {};
        const unsigned short* Kr = Kp + (kvh * 32 + l31) * 128;
#pragma unroll
        for (int ks = 0; ks < 8; ++ks) {
            int g = (ks * 2 + h8) ^ (l31 & 15);
            bf16x8 kf = *(const bf16x8*)((const __bf16*)Kr + g * 8);
            s = __builtin_amdgcn_mfma_f32_32x32x16_bf16(kf, qfrag[ks], s, 0, 0, 0);
        }

        // softmax (static max), mask on diagonal tile
        if (j == jmask) {
#pragma unroll
            for (int r = 0; r < 16; ++r) {
                float pv = exp2f(s[r] * cs);
                int kvg = j * 64 + rowbase + (r & 3) + 8 * (r >> 2);
                if (kvg > qglob) pv = 0.f;
                l_part += pv;
                s[r] = pv;
            }
        } else {
#pragma unroll
            for (int r = 0; r < 16; ++r) {
                float pv = exp2f(s[r] * cs);
                l_part += pv;
                s[r] = pv;
            }
        }

        // pack P to bf16 in-register: 8 cvt_pk + 4 permlane32_swap.
        // lane h holds kv = c+4h, c in {0..3,8..11,16..19,24..27}; swap (w0,w2),
        // (w1,w3) yields contiguous kv chunks [8h,8h+8) and [16+8h,16+8h+8).
        unsigned int w0, w1, w2, w3, w4, w5, w6, w7;
        asm("v_cvt_pk_bf16_f32 %0, %1, %2" : "=v"(w0) : "v"(s[0]), "v"(s[1]));
        asm("v_cvt_pk_bf16_f32 %0, %1, %2" : "=v"(w1) : "v"(s[2]), "v"(s[3]));
        asm("v_cvt_pk_bf16_f32 %0, %1, %2" : "=v"(w2) : "v"(s[4]), "v"(s[5]));
        asm("v_cvt_pk_bf16_f32 %0, %1, %2" : "=v"(w3) : "v"(s[6]), "v"(s[7]));
        asm("v_cvt_pk_bf16_f32 %0, %1, %2" : "=v"(w4) : "v"(s[8]), "v"(s[9]));
        asm("v_cvt_pk_bf16_f32 %0, %1, %2" : "=v"(w5) : "v"(s[10]), "v"(s[11]));
        asm("v_cvt_pk_bf16_f32 %0, %1, %2" : "=v"(w6) : "v"(s[12]), "v"(s[13]));
        asm("v_cvt_pk_bf16_f32 %0, %1, %2" : "=v"(w7) : "v"(s[14]), "v"(s[15]));
        asm("v_permlane32_swap_b32 %0, %1" : "+v"(w0), "+v"(w2));
        asm("v_permlane32_swap_b32 %0, %1" : "+v"(w1), "+v"(w3));
        asm("v_permlane32_swap_b32 %0, %1" : "+v"(w4), "+v"(w6));
        asm("v_permlane32_swap_b32 %0, %1" : "+v"(w5), "+v"(w7));
        u32x4 a0v = {w0, w1, w2, w3};
        u32x4 a1v = {w4, w5, w6, w7};
        bf16x8 pa0 = __builtin_bit_cast(bf16x8, a0v);
        bf16x8 pa1 = __builtin_bit_cast(bf16x8, a1v);

        // O += P V : 4 d-blocks x 2 ksteps; B = V^T frags from LDS
#pragma unroll
        for (int ks2 = 0; ks2 < 2; ++ks2) {
            bf16x8 pf = (ks2 == 0) ? pa0 : pa1;
#pragma unroll
            for (int dblk = 0; dblk < 4; ++dblk) {
                int d = dblk * 32 + l31;
                int vg = (kvh * 4 + ks2 * 2 + h8) ^ (d & 7);
                bf16x8 vf = *(const bf16x8*)((const __bf16*)Vp + d * 64 + vg * 8);
                oacc[dblk] = __builtin_amdgcn_mfma_f32_32x32x16_bf16(pf, vf, oacc[dblk], 0, 0, 0);
            }
        }
    }
}

__device__ __forceinline__ void load_qfrag(const unsigned short* qB, int q0,
                                           int qh, int lane, bf16x8 qf[8]) {
    const int l31 = lane & 31, h8 = lane >> 5;
    const unsigned short* qrow = qB + (size_t)(q0 + qh * 32 + l31) * H_ + h8 * 8;
#pragma unroll
    for (int ks = 0; ks < 8; ++ks) qf[ks] = *(const bf16x8*)(qrow + ks * 16);
}

// cross-kvh reduce: in-lane-pair l reduce, kvh=1 waves publish O,l via
// XOR-swizzled LDS scratch (over Ks), kvh=0 waves accumulate. Once per segment.
__device__ __forceinline__ void xgroup_reduce(
    float& l_part, f32x16 oacc[4], unsigned short* KsBase, float* Lred,
    int lane, int qh, int kvh) {
    l_part += __shfl_xor(l_part, 32);
    __syncthreads();  // all waves done reading K/V LDS
    float* base = (float*)KsBase + (size_t)(qh * 64 + lane) * 64;
    if (kvh == 1) {
#pragma unroll
        for (int dblk = 0; dblk < 4; ++dblk)
#pragma unroll
            for (int part = 0; part < 4; ++part) {
                int c = dblk * 4 + part;
                f32x4 v = {oacc[dblk][part * 4 + 0], oacc[dblk][part * 4 + 1],
                           oacc[dblk][part * 4 + 2], oacc[dblk][part * 4 + 3]};
                *(f32x4*)(base + ((c ^ (lane & 15)) * 4)) = v;
            }
        if (lane < 32) Lred[qh * 32 + lane] = l_part;
    }
    __syncthreads();
    if (kvh == 0) {
#pragma unroll
        for (int dblk = 0; dblk < 4; ++dblk)
#pragma unroll
            for (int part = 0; part < 4; ++part) {
                int c = dblk * 4 + part;
                f32x4 v = *(const f32x4*)(base + ((c ^ (lane & 15)) * 4));
                oacc[dblk][part * 4 + 0] += v[0];
                oacc[dblk][part * 4 + 1] += v[1];
                oacc[dblk][part * 4 + 2] += v[2];
                oacc[dblk][part * 4 + 3] += v[3];
            }
        l_part += Lred[qh * 32 + (lane & 31)];
    }
}

// ---- kernel 3: balanced causal flash attention, 4 waves of 32x32 MFMA.
__global__ __launch_bounds__(256, 2) void attn_kernel(
    const unsigned short* __restrict__ qb, const unsigned short* __restrict__ kb,
    const unsigned short* __restrict__ vtb, float* __restrict__ out,
    float* __restrict__ pO, float* __restrict__ pL) {
    __shared__ unsigned short Ks[2][64 * 128];   // 32 KB (also reduce scratch)
    __shared__ unsigned short Vs[2][128 * 64];   // 32 KB
    __shared__ float Lred[64];

    const int tid = threadIdx.x;
    const int bid = blockIdx.x;
    const int half = bid >> 8;
    const int slot = bid & 255;
    const int r = slot >> 4;
    const int b = slot & 15;

    const unsigned short* qB = qb + (size_t)b * T_ * H_;
    const unsigned short* kB = kb + (size_t)b * T_ * H_;
    const unsigned short* vB = vtb + (size_t)b * H_ * T_;

    const int wid = tid >> 6;
    const int lane = tid & 63;
    const int l31 = lane & 31;
    const int h8 = lane >> 5;
    const int qh = wid & 1;     // q 32-col block within 64-row q tile
    const int kvh = wid >> 1;   // kv-half of each 64-row kv tile

    const int qtb = 31 - r;
    bf16x8 qf[8];
    float l_part = 0.f;
    f32x16 oacc[4] = {};

    if (half == 0) {
        // tile A (qt = r): full, direct output
        load_qfrag(qB, r * 64, qh, lane, qf);
        attn_seg(kB, vB, qf, 0, r + 1, r, r * 64 + qh * 32, l_part, oacc,
                 &Ks[0][0], &Vs[0][0], tid, wid, lane, qh, kvh);
        xgroup_reduce(l_part, oacc, &Ks[0][0], Lred, lane, qh, kvh);
        if (kvh == 0) {
            float* outb = out + (size_t)b * T_ * H_;
#pragma unroll
            for (int rr = 0; rr < 16; ++rr) {
                int ql = (rr & 3) + 8 * (rr >> 2) + 4 * h8;
                float inv = 1.0f / __shfl(l_part, ql);
                float* orow = outb + (size_t)(r * 64 + qh * 32 + ql) * H_;
#pragma unroll
                for (int dblk = 0; dblk < 4; ++dblk)
                    orow[dblk * 32 + l31] = oacc[dblk][rr] * inv;
            }
        }
        // tile B (qt = 31-r): kv units [0, 16-r), partial
        l_part = 0.f;
#pragma unroll
        for (int dblk = 0; dblk < 4; ++dblk)
#pragma unroll
            for (int e = 0; e < 16; ++e) oacc[dblk][e] = 0.f;
        load_qfrag(qB, qtb * 64, qh, lane, qf);
        attn_seg(kB, vB, qf, 0, 16 - r, -1, qtb * 64 + qh * 32, l_part, oacc,
                 &Ks[0][0], &Vs[0][0], tid, wid, lane, qh, kvh);
    } else {
        // tile B: kv units [16-r, 32-r), includes diagonal at j=31-r
        load_qfrag(qB, qtb * 64, qh, lane, qf);
        attn_seg(kB, vB, qf, 16 - r, 32 - r, qtb, qtb * 64 + qh * 32, l_part, oacc,
                 &Ks[0][0], &Vs[0][0], tid, wid, lane, qh, kvh);
    }

    // cross-kvh reduce + partial store for tile B (kvh==0 waves write)
    xgroup_reduce(l_part, oacc, &Ks[0][0], Lred, lane, qh, kvh);
    if (kvh == 0) {
        float* myO = pO + (size_t)(half * 256 + slot) * (64 * 128);
        if (lane < 32) pL[(half * 256 + slot) * 64 + qh * 32 + lane] = l_part;
#pragma unroll
        for (int rr = 0; rr < 16; ++rr) {
            int ql = qh * 32 + (rr & 3) + 8 * (rr >> 2) + 4 * h8;
#pragma unroll
            for (int dblk = 0; dblk < 4; ++dblk)
                myO[ql * 128 + dblk * 32 + l31] = oacc[dblk][rr];
        }
    }
}

// ---- kernel 4: combine split partials for q-tiles 16..31
__global__ __launch_bounds__(256) void combine_kernel(
    const float* __restrict__ pO, const float* __restrict__ pL,
    float* __restrict__ out) {
    const int slot = blockIdx.x;
    const int r = slot >> 4;
    const int b = slot & 15;
    const int q0 = (31 - r) * 64;
    __shared__ float ls[64];
    const int tid = threadIdx.x;
    if (tid < 64) ls[tid] = pL[slot * 64 + tid] + pL[(256 + slot) * 64 + tid];
    __syncthreads();
    const float* O0 = pO + (size_t)slot * (64 * 128);
    const float* O1 = pO + (size_t)(256 + slot) * (64 * 128);
    float* ob = out + ((size_t)b * T_ + q0) * H_;
#pragma unroll
    for (int k = 0; k < 8; ++k) {
        int idx = (k * 256 + tid) * 4;
        f32x4 a = *(const f32x4*)(O0 + idx);
        f32x4 c = *(const f32x4*)(O1 + idx);
        float inv = 1.0f / ls[idx >> 7];
        f32x4 o;
        o[0] = (a[0] + c[0]) * inv; o[1] = (a[1] + c[1]) * inv;
        o[2] = (a[2] + c[2]) * inv; o[3] = (a[3] + c[3]) * inv;
        *(f32x4*)(ob + idx) = o;
    }
}

extern "C" void kernel_launch(void* const* d_in, const int* in_sizes, int n_in,
                              void* d_out, int out_size, void* d_ws, size_t ws_size,
                              hipStream_t stream) {
    const float* x = (const float*)d_in[0];
    const float* Wq = (const float*)d_in[1];
    const float* Wk = (const float*)d_in[2];
    const float* Wv = (const float*)d_in[3];
    float* out = (float*)d_out;

    char* ws = (char*)d_ws;
    unsigned short* wT  = (unsigned short*)ws;                    // 576 KB
    unsigned short* qb  = (unsigned short*)(ws + (1ull << 20));   // 8 MB
    unsigned short* kb  = (unsigned short*)(ws + (9ull << 20));   // 8 MB
    unsigned short* vtb = (unsigned short*)(ws + (17ull << 20));  // 8 MB
    float* pO = (float*)(ws + (80ull << 20));                     // 16.8 MB
    float* pL = (float*)(ws + (100ull << 20));                    // 128 KB

    hipLaunchKernelGGL(wconv_kernel, dim3(1152), dim3(256), 0, stream, Wq, Wk, Wv, wT);
    hipLaunchKernelGGL(proj_kernel, dim3(512), dim3(512), 0, stream, x, wT, qb, kb, vtb);
    hipLaunchKernelGGL(attn_kernel, dim3(512), dim3(256), 0, stream, qb, kb, vtb, out, pO, pL);
    hipLaunchKernelGGL(combine_kernel, dim3(256), dim3(256), 0, stream, pO, pL, out);
}